// Round 5
// baseline (115.659 us; speedup 1.0000x reference)
//
#include <hip/hip_runtime.h>
#include <cstddef>

// InfoNCE loss, B=8192, D=128.
// prep: normalize + bf16 cast + (label, conf-sign) + self-dot (+ accum zero)
// sim:  PERSISTENT blocks (768 = 3/CU co-resident), each loops over symmetric
//       superblock pairs (R<=C) strided by gridDim. Next pair's B-stripe is
//       prefetched into registers during current pair's compute, then written
//       to the single swizzled LDS tile after the flush barrier.
//       No global atomics: pair (R,C) writes part[C][stripe R rows] (row-view)
//       and part[R][stripe C rows] (col-view, ex_ij ~= ex_ji), each exactly once.
// fin1: per-row slot-sum + loss, block-reduce, 2 atomics/block into accum
// fin2: out = sum/cnt

#define DDIM 128
#define TEMP_SCALE 14.4269504088896340736f  // (1/0.1) * log2(e), folded into A-side
#define BIGNEG 5e29f

typedef short s8bf __attribute__((ext_vector_type(8)));   // 8 bf16 (4 VGPRs)
typedef float f32x4 __attribute__((ext_vector_type(4)));

__device__ __forceinline__ unsigned short f2bf(float f) {
    unsigned int u = __float_as_uint(f);
    u += 0x7fffu + ((u >> 16) & 1u);
    return (unsigned short)(u >> 16);
}
__device__ __forceinline__ float bf2f(unsigned short h) {
    return __uint_as_float(((unsigned int)h) << 16);
}

__device__ __forceinline__ void decode_pair(int n, int T, int& R, int& C) {
    float fT = (float)T;
    float disc = (2.f * fT + 1.f) * (2.f * fT + 1.f) - 8.f * (float)n;
    int r = (int)((2.f * fT + 1.f - sqrtf(disc)) * 0.5f);
    if (r > 0 && r * T - r * (r - 1) / 2 > n) --r;
    while ((r + 1) * T - (r + 1) * r / 2 <= n) ++r;
    R = r;
    C = r + (n - (r * T - r * (r - 1) / 2));
}

// ---------------- prep: one wave per row ----------------
__global__ __launch_bounds__(256) void prep_kernel(
    const float* __restrict__ emb, const int* __restrict__ labels,
    const float* __restrict__ conf,
    short* __restrict__ Ea,   // bf16(SCALE * e)
    short* __restrict__ Eb,   // bf16(e)
    float2* __restrict__ lh,  // (label +-1, sign(conf))
    float* __restrict__ sd,   // scaled self-dot (bf16-rounded)
    float* __restrict__ accum, int B)
{
    if (blockIdx.x == 0 && threadIdx.x == 0) { accum[0] = 0.0f; accum[1] = 0.0f; }

    int wave = threadIdx.x >> 6;
    int lane = threadIdx.x & 63;
    int row  = blockIdx.x * 4 + wave;
    if (row >= B) return;

    float2 x = ((const float2*)(emb + (size_t)row * DDIM))[lane];
    float ss = x.x * x.x + x.y * x.y;
    #pragma unroll
    for (int m = 32; m; m >>= 1) ss += __shfl_xor(ss, m);
    float inv = 1.0f / fmaxf(sqrtf(ss), 1e-12f);

    float e0 = x.x * inv, e1 = x.y * inv;
    unsigned short ea0 = f2bf(TEMP_SCALE * e0), ea1 = f2bf(TEMP_SCALE * e1);
    unsigned short eb0 = f2bf(e0),              eb1 = f2bf(e1);
    *(ushort2*)(Ea + (size_t)row * DDIM + lane * 2) = make_ushort2(ea0, ea1);
    *(ushort2*)(Eb + (size_t)row * DDIM + lane * 2) = make_ushort2(eb0, eb1);

    float p = bf2f(ea0) * bf2f(eb0) + bf2f(ea1) * bf2f(eb1);
    #pragma unroll
    for (int m = 32; m; m >>= 1) p += __shfl_xor(p, m);

    if (lane == 0) {
        sd[row] = p;
        float l = labels[row] ? 1.0f : -1.0f;
        float c = conf[row];
        float h = (c > 0.0f) ? 1.0f : ((c < 0.0f) ? -1.0f : 0.0f);
        lh[row] = make_float2(l, h);
    }
}

// ---------------- sim ----------------
__global__ __launch_bounds__(256, 3) void sim_kernel(
    const short* __restrict__ Ea, const short* __restrict__ Eb,
    const float2* __restrict__ lh,
    float* __restrict__ tpart, float* __restrict__ ppart,
    int B, int T)   // T = B/128 stripes
{
    __shared__ int4  tile16[128 * 16];   // 32 KB, chunk c of row r at c^(r&15)
    __shared__ float2 lhTile[128];
    __shared__ float rT[128], rP[128];           // row-view per-row results
    __shared__ float cTl[4][128], cPl[4][128];   // col-view per-wave partials

    int tid  = threadIdx.x;
    int lane = tid & 63;
    int wave = tid >> 6;
    int l16  = lane & 15;
    int quad = lane >> 4;
    int npairs = T * (T + 1) / 2;

    int p = blockIdx.x;
    if (p >= npairs) return;
    int R, C;
    decode_pair(p, T, R, C);

    // ---- initial stage of tile for first pair ----
    {
        const int4* gsrc = (const int4*)(Eb + (size_t)(C * 128) * DDIM);
        int4 v[8];
        #pragma unroll
        for (int i = 0; i < 8; ++i) v[i] = gsrc[i * 256 + tid];
        float2 lv;
        if (tid < 128) lv = lh[C * 128 + tid];
        #pragma unroll
        for (int i = 0; i < 8; ++i) {
            int chunk = i * 256 + tid;
            int row = chunk >> 4, off = chunk & 15;
            tile16[row * 16 + (off ^ (row & 15))] = v[i];
        }
        if (tid < 128) lhTile[tid] = lv;
    }
    __syncthreads();

    while (true) {
        int pn = p + gridDim.x;
        bool hasNext = pn < npairs;
        int Rn = 0, Cn = 0;
        if (hasNext) decode_pair(pn, T, Rn, Cn);

        int rowBase = R * 128 + wave * 32;

        // A fragments for current pair: A[m=l16][k=quad*8+j]
        s8bf a0[4], a1[4];
        #pragma unroll
        for (int kc = 0; kc < 4; ++kc) {
            a0[kc] = *(const s8bf*)(Ea + (size_t)(rowBase +      l16) * DDIM + kc * 32 + quad * 8);
            a1[kc] = *(const s8bf*)(Ea + (size_t)(rowBase + 16 + l16) * DDIM + kc * 32 + quad * 8);
        }
        // per-reg row constants (C/D layout: col = lane&15, row = quad*4 + reg)
        float hi0[4], hi1[4], mP0[4], mP1[4];
        #pragma unroll
        for (int r = 0; r < 4; ++r) {
            float2 v0 = lh[rowBase +      quad * 4 + r];
            float2 v1 = lh[rowBase + 16 + quad * 4 + r];
            hi0[r] = v0.y; mP0[r] = (v0.x > 0.0f) ? 1.0f : 0.0f;
            hi1[r] = v1.y; mP1[r] = (v1.x > 0.0f) ? 1.0f : 0.0f;
        }

        // ---- prefetch next pair's B-stripe into registers (hidden by compute) ----
        int4 pf[8];
        float2 lpf;
        if (hasNext) {
            const int4* gsrc = (const int4*)(Eb + (size_t)(Cn * 128) * DDIM);
            #pragma unroll
            for (int i = 0; i < 8; ++i) pf[i] = gsrc[i * 256 + tid];
            if (tid < 128) lpf = lh[Cn * 128 + tid];
        }

        float tot0[4] = {0,0,0,0}, tP0[4] = {0,0,0,0};
        float tot1[4] = {0,0,0,0}, tP1[4] = {0,0,0,0};
        float cT[8]   = {0,0,0,0,0,0,0,0}, cP[8] = {0,0,0,0,0,0,0,0};

        #pragma unroll
        for (int ct = 0; ct < 8; ++ct) {
            s8bf b[4];
            #pragma unroll
            for (int kc = 0; kc < 4; ++kc)
                b[kc] = *(const s8bf*)&tile16[(ct * 16 + l16) * 16 + ((kc * 4 + quad) ^ l16)];

            f32x4 acc0 = {0.f,0.f,0.f,0.f}, acc1 = {0.f,0.f,0.f,0.f};
            #pragma unroll
            for (int kc = 0; kc < 4; ++kc) {
                acc0 = __builtin_amdgcn_mfma_f32_16x16x32_bf16(a0[kc], b[kc], acc0, 0, 0, 0);
                acc1 = __builtin_amdgcn_mfma_f32_16x16x32_bf16(a1[kc], b[kc], acc1, 0, 0, 0);
            }

            float2 lhj = lhTile[ct * 16 + l16];
            float bp  = BIGNEG * lhj.y;                 // 5e29 * h_j
            float mPc = fmaf(lhj.x, 0.5f, 0.5f);        // (l_j>0)?1:0
            #pragma unroll
            for (int r = 0; r < 4; ++r) {
                float e0 = __builtin_amdgcn_exp2f(acc0[r] + fmaf(hi0[r], bp, -BIGNEG));
                tot0[r] += e0;
                tP0[r]  = fmaf(mPc, e0, tP0[r]);
                cT[ct] += e0;
                cP[ct]  = fmaf(mP0[r], e0, cP[ct]);

                float e1 = __builtin_amdgcn_exp2f(acc1[r] + fmaf(hi1[r], bp, -BIGNEG));
                tot1[r] += e1;
                tP1[r]  = fmaf(mPc, e1, tP1[r]);
                cT[ct] += e1;
                cP[ct]  = fmaf(mP1[r], e1, cP[ct]);
            }
        }

        // ---- row-view: butterfly over 16 col-lanes -> LDS (resolved pos) ----
        #pragma unroll
        for (int r = 0; r < 4; ++r) {
            float t0 = tot0[r], p0 = tP0[r], t1 = tot1[r], p1 = tP1[r];
            #pragma unroll
            for (int m = 1; m < 16; m <<= 1) {
                t0 += __shfl_xor(t0, m); p0 += __shfl_xor(p0, m);
                t1 += __shfl_xor(t1, m); p1 += __shfl_xor(p1, m);
            }
            if (l16 == 0) {
                int o0 = wave * 32 +      quad * 4 + r;
                int o1 = wave * 32 + 16 + quad * 4 + r;
                float li0 = lh[R * 128 + o0].x, li1 = lh[R * 128 + o1].x;
                rT[o0] = t0; rP[o0] = (li0 > 0.0f) ? p0 : (t0 - p0);
                rT[o1] = t1; rP[o1] = (li1 > 0.0f) ? p1 : (t1 - p1);
            }
        }

        // ---- col-view: reduce over quads, per-wave partials -> LDS ----
        #pragma unroll
        for (int ct = 0; ct < 8; ++ct) {
            float t = cT[ct], pp = cP[ct];
            t  += __shfl_xor(t, 16);  t  += __shfl_xor(t, 32);
            pp += __shfl_xor(pp, 16); pp += __shfl_xor(pp, 32);
            if (lane < 16) {
                int o = ct * 16 + lane;
                float lj = lhTile[o].x;
                cTl[wave][o] = t;
                cPl[wave][o] = (lj > 0.0f) ? pp : (t - pp);
            }
        }

        __syncthreads();   // flush data ready; all waves done reading tile16/lhTile

        // ---- coalesced slot stores: (stripe,slot) written exactly once ----
        if (tid < 128) {
            tpart[(size_t)C * B + R * 128 + tid] = rT[tid];
            if (R != C)
                tpart[(size_t)R * B + C * 128 + tid] =
                    cTl[0][tid] + cTl[1][tid] + cTl[2][tid] + cTl[3][tid];
        } else {
            int t2 = tid - 128;
            ppart[(size_t)C * B + R * 128 + t2] = rP[t2];
            if (R != C)
                ppart[(size_t)R * B + C * 128 + t2] =
                    cPl[0][t2] + cPl[1][t2] + cPl[2][t2] + cPl[3][t2];
        }

        // ---- restage: write prefetched regs into the tile ----
        if (!hasNext) break;
        #pragma unroll
        for (int i = 0; i < 8; ++i) {
            int chunk = i * 256 + tid;
            int row = chunk >> 4, off = chunk & 15;
            tile16[row * 16 + (off ^ (row & 15))] = pf[i];
        }
        if (tid < 128) lhTile[tid] = lpf;
        __syncthreads();

        p = pn; R = Rn; C = Cn;
    }
}

// ---------------- fin1: slot-sum + per-row loss + block reduce ----------------
__global__ __launch_bounds__(256) void fin1_kernel(
    const float* __restrict__ tpart, const float* __restrict__ ppart,
    const float* __restrict__ sd, const float2* __restrict__ lh,
    float* __restrict__ accum, int B, int T)
{
    __shared__ float ssum[4], scnt[4];
    int i = blockIdx.x * 256 + threadIdx.x;

    float tot = 0.0f, pos = 0.0f;
    #pragma unroll 4
    for (int s = 0; s < T; ++s) {
        tot += tpart[(size_t)s * B + i];
        pos += ppart[(size_t)s * B + i];
    }
    float diag = (lh[i].y != 0.0f) ? __builtin_amdgcn_exp2f(sd[i]) : 0.0f;
    float p   = pos - diag;
    float neg = tot - pos;     // diag cancels (in both tot and pos)
    float sum = 0.0f, cnt = 0.0f;
    if (p > 0.0f && neg > 0.0f) {
        sum = 0.69314718055994530942f *
              (__builtin_amdgcn_logf(p + neg + 1e-8f) - __builtin_amdgcn_logf(p));
        cnt = 1.0f;
    }
    #pragma unroll
    for (int m = 32; m; m >>= 1) {
        sum += __shfl_xor(sum, m);
        cnt += __shfl_xor(cnt, m);
    }
    int wave = threadIdx.x >> 6, lane = threadIdx.x & 63;
    if (lane == 0) { ssum[wave] = sum; scnt[wave] = cnt; }
    __syncthreads();
    if (threadIdx.x == 0) {
        atomicAdd(&accum[0], ssum[0] + ssum[1] + ssum[2] + ssum[3]);
        atomicAdd(&accum[1], scnt[0] + scnt[1] + scnt[2] + scnt[3]);
    }
}

__global__ void fin2_kernel(const float* __restrict__ accum, float* __restrict__ out) {
    float S = accum[0], C = accum[1];
    out[0] = (C > 0.0f) ? S / fmaxf(C, 1.0f) : 0.0f;
}

extern "C" void kernel_launch(void* const* d_in, const int* in_sizes, int n_in,
                              void* d_out, int out_size, void* d_ws, size_t ws_size,
                              hipStream_t stream) {
    const float* emb    = (const float*)d_in[0];
    const int*   labels = (const int*)d_in[1];
    const float* conf   = (const float*)d_in[2];
    float* out = (float*)d_out;
    int B = in_sizes[1];   // 8192
    int T = B / 128;       // 64 stripes

    char* ws = (char*)d_ws;
    size_t off = 0;
    short*  Ea    = (short*)(ws + off);  off += (size_t)B * DDIM * 2;
    short*  Eb    = (short*)(ws + off);  off += (size_t)B * DDIM * 2;
    float2* lhp   = (float2*)(ws + off); off += (size_t)B * 8;
    float*  sd    = (float*)(ws + off);  off += (size_t)B * 4;
    float*  tpart = (float*)(ws + off);  off += (size_t)T * B * 4;
    float*  ppart = (float*)(ws + off);  off += (size_t)T * B * 4;
    float*  accum = (float*)(ws + off);  off += 64;

    prep_kernel<<<B / 4, 256, 0, stream>>>(emb, labels, conf, Ea, Eb, lhp, sd, accum, B);

    // persistent: 768 blocks = 3/CU co-resident (LDS 38.9KB, VGPR capped by
    // __launch_bounds__(256,3)); each strides the 2080-pair list by gridDim.
    sim_kernel<<<768, 256, 0, stream>>>(Ea, Eb, lhp, tpart, ppart, B, T);

    fin1_kernel<<<B / 256, 256, 0, stream>>>(tpart, ppart, sd, lhp, accum, B, T);
    fin2_kernel<<<1, 1, 0, stream>>>(accum, out);
}

// Round 6
// 106.431 us; speedup vs baseline: 1.0867x; 1.0867x over previous
//
#include <hip/hip_runtime.h>
#include <cstddef>

// InfoNCE loss, B=8192, D=128.
// prep: normalize + bf16 cast + (label, conf-sign) + self-dot (+ accum zero)
// sim:  persistent blocks (512 = 2/CU), each owns a CONSECUTIVE range of
//       symmetric superblock pairs (R<=C, C-fastest). B-stripe staged via
//       async global_load_lds DMA into a DOUBLE-BUFFERED XOR-swizzled LDS
//       tile (swizzle realized by permuting per-lane source addresses —
//       zero VGPR cost, no spill). Next pair's DMA issued before current
//       pair's compute. No global atomics: pair (R,C) writes
//       part[C][stripe R rows] (row-view) and part[R][stripe C rows]
//       (col-view, ex_ij ~= ex_ji), each slot exactly once.
// fin1: per-row slot-sum + loss, block-reduce, 2 atomics/block into accum
// fin2: out = sum/cnt

#define DDIM 128
#define TEMP_SCALE 14.4269504088896340736f  // (1/0.1) * log2(e), folded into A-side
#define BIGNEG 5e29f

typedef short s8bf __attribute__((ext_vector_type(8)));   // 8 bf16 (4 VGPRs)
typedef float f32x4 __attribute__((ext_vector_type(4)));

__device__ __forceinline__ unsigned short f2bf(float f) {
    unsigned int u = __float_as_uint(f);
    u += 0x7fffu + ((u >> 16) & 1u);
    return (unsigned short)(u >> 16);
}
__device__ __forceinline__ float bf2f(unsigned short h) {
    return __uint_as_float(((unsigned int)h) << 16);
}

__device__ __forceinline__ void decode_pair(int n, int T, int& R, int& C) {
    float fT = (float)T;
    float disc = (2.f * fT + 1.f) * (2.f * fT + 1.f) - 8.f * (float)n;
    int r = (int)((2.f * fT + 1.f - sqrtf(disc)) * 0.5f);
    if (r > 0 && r * T - r * (r - 1) / 2 > n) --r;
    while ((r + 1) * T - (r + 1) * r / 2 <= n) ++r;
    R = r;
    C = r + (n - (r * T - r * (r - 1) / 2));
}

// ---------------- prep: one wave per row ----------------
__global__ __launch_bounds__(256) void prep_kernel(
    const float* __restrict__ emb, const int* __restrict__ labels,
    const float* __restrict__ conf,
    short* __restrict__ Ea,   // bf16(SCALE * e)
    short* __restrict__ Eb,   // bf16(e)
    float2* __restrict__ lh,  // (label +-1, sign(conf))
    float* __restrict__ sd,   // scaled self-dot (bf16-rounded)
    float* __restrict__ accum, int B)
{
    if (blockIdx.x == 0 && threadIdx.x == 0) { accum[0] = 0.0f; accum[1] = 0.0f; }

    int wave = threadIdx.x >> 6;
    int lane = threadIdx.x & 63;
    int row  = blockIdx.x * 4 + wave;
    if (row >= B) return;

    float2 x = ((const float2*)(emb + (size_t)row * DDIM))[lane];
    float ss = x.x * x.x + x.y * x.y;
    #pragma unroll
    for (int m = 32; m; m >>= 1) ss += __shfl_xor(ss, m);
    float inv = 1.0f / fmaxf(sqrtf(ss), 1e-12f);

    float e0 = x.x * inv, e1 = x.y * inv;
    unsigned short ea0 = f2bf(TEMP_SCALE * e0), ea1 = f2bf(TEMP_SCALE * e1);
    unsigned short eb0 = f2bf(e0),              eb1 = f2bf(e1);
    *(ushort2*)(Ea + (size_t)row * DDIM + lane * 2) = make_ushort2(ea0, ea1);
    *(ushort2*)(Eb + (size_t)row * DDIM + lane * 2) = make_ushort2(eb0, eb1);

    float p = bf2f(ea0) * bf2f(eb0) + bf2f(ea1) * bf2f(eb1);
    #pragma unroll
    for (int m = 32; m; m >>= 1) p += __shfl_xor(p, m);

    if (lane == 0) {
        sd[row] = p;
        float l = labels[row] ? 1.0f : -1.0f;
        float c = conf[row];
        float h = (c > 0.0f) ? 1.0f : ((c < 0.0f) ? -1.0f : 0.0f);
        lh[row] = make_float2(l, h);
    }
}

// ---------------- sim ----------------
// Async DMA stage of stripe C into swizzled LDS buffer. LDS side of
// global_load_lds is wave-uniform-base + lane*16; the XOR swizzle
// (chunk c of row r lands at c^(r&15)) is realized by permuting the
// per-lane SOURCE address: LDS slot s holds global chunk
// (s & ~15) | ((s ^ (s>>4)) & 15).
__device__ __forceinline__ void stage_async(
    const short* __restrict__ Eb, const float2* __restrict__ lh, int C,
    int wave, int lane, int4* tileBuf, float2* lhBuf)
{
    const char* gbase = (const char*)Eb + (size_t)C * 128 * DDIM * sizeof(short);
    #pragma unroll
    for (int i = 0; i < 8; ++i) {
        int s = (wave * 8 + i) * 64 + lane;
        int srcChunk = (s & ~15) | ((s ^ (s >> 4)) & 15);
        __builtin_amdgcn_global_load_lds(
            (const __attribute__((address_space(1))) void*)(gbase + (size_t)srcChunk * 16),
            (__attribute__((address_space(3))) void*)((char*)tileBuf + (size_t)(wave * 8 + i) * 1024),
            16, 0, 0);
    }
    if (wave == 0) {
        __builtin_amdgcn_global_load_lds(
            (const __attribute__((address_space(1))) void*)((const char*)(lh + (size_t)C * 128) + lane * 16),
            (__attribute__((address_space(3))) void*)lhBuf,
            16, 0, 0);
    }
}

__global__ __launch_bounds__(256, 2) void sim_kernel(
    const short* __restrict__ Ea, const short* __restrict__ Eb,
    const float2* __restrict__ lh,
    float* __restrict__ tpart, float* __restrict__ ppart,
    int B, int T)   // T = B/128 stripes
{
    __shared__ int4  tiles[2][128 * 16];         // 2 x 32 KB, swizzled
    __shared__ float2 lhT[2][128];               // 2 x 1 KB
    __shared__ float rT[128], rP[128];           // row-view per-row results
    __shared__ float cTl[4][128], cPl[4][128];   // col-view per-wave partials

    int tid  = threadIdx.x;
    int lane = tid & 63;
    int wave = tid >> 6;
    int l16  = lane & 15;
    int quad = lane >> 4;

    int npairs = T * (T + 1) / 2;
    int pstart = (int)(((long)blockIdx.x * npairs) / gridDim.x);
    int pend   = (int)(((long)(blockIdx.x + 1) * npairs) / gridDim.x);
    if (pstart >= pend) return;

    int R, C;
    decode_pair(pstart, T, R, C);

    stage_async(Eb, lh, C, wave, lane, tiles[0], lhT[0]);
    __syncthreads();   // vmcnt(0) drain: buf0 ready

    int cur = 0;
    int lastR = -1;
    s8bf a0[4], a1[4];
    float hi0[4], hi1[4], mP0[4], mP1[4];

    for (int p = pstart; p < pend; ++p) {
        // next pair (C-fastest within R)
        int Rn = R, Cn = C + 1;
        if (Cn == T) { Rn = R + 1; Cn = Rn; }
        bool hasNext = (p + 1) < pend;

        // ---- issue next pair's DMA; overlaps the compute below ----
        if (hasNext)
            stage_async(Eb, lh, Cn, wave, lane, tiles[cur ^ 1], lhT[cur ^ 1]);

        // ---- A fragments + row constants (reload only when R changes) ----
        if (R != lastR) {
            int rowBase = R * 128 + wave * 32;
            #pragma unroll
            for (int kc = 0; kc < 4; ++kc) {
                a0[kc] = *(const s8bf*)(Ea + (size_t)(rowBase +      l16) * DDIM + kc * 32 + quad * 8);
                a1[kc] = *(const s8bf*)(Ea + (size_t)(rowBase + 16 + l16) * DDIM + kc * 32 + quad * 8);
            }
            #pragma unroll
            for (int r = 0; r < 4; ++r) {
                float2 v0 = lh[rowBase +      quad * 4 + r];
                float2 v1 = lh[rowBase + 16 + quad * 4 + r];
                hi0[r] = v0.y; mP0[r] = (v0.x > 0.0f) ? 1.0f : 0.0f;
                hi1[r] = v1.y; mP1[r] = (v1.x > 0.0f) ? 1.0f : 0.0f;
            }
            lastR = R;
        }

        const int4*   tile16 = tiles[cur];
        const float2* lhTile = lhT[cur];

        float tot0[4] = {0,0,0,0}, tP0[4] = {0,0,0,0};
        float tot1[4] = {0,0,0,0}, tP1[4] = {0,0,0,0};
        float cT[8]   = {0,0,0,0,0,0,0,0}, cP[8] = {0,0,0,0,0,0,0,0};

        #pragma unroll
        for (int ct = 0; ct < 8; ++ct) {
            s8bf b[4];
            #pragma unroll
            for (int kc = 0; kc < 4; ++kc)
                b[kc] = *(const s8bf*)&tile16[(ct * 16 + l16) * 16 + ((kc * 4 + quad) ^ l16)];

            f32x4 acc0 = {0.f,0.f,0.f,0.f}, acc1 = {0.f,0.f,0.f,0.f};
            #pragma unroll
            for (int kc = 0; kc < 4; ++kc) {
                acc0 = __builtin_amdgcn_mfma_f32_16x16x32_bf16(a0[kc], b[kc], acc0, 0, 0, 0);
                acc1 = __builtin_amdgcn_mfma_f32_16x16x32_bf16(a1[kc], b[kc], acc1, 0, 0, 0);
            }

            float2 lhj = lhTile[ct * 16 + l16];
            float bp  = BIGNEG * lhj.y;                 // 5e29 * h_j
            float mPc = fmaf(lhj.x, 0.5f, 0.5f);        // (l_j>0)?1:0
            #pragma unroll
            for (int r = 0; r < 4; ++r) {
                float e0 = __builtin_amdgcn_exp2f(acc0[r] + fmaf(hi0[r], bp, -BIGNEG));
                tot0[r] += e0;
                tP0[r]  = fmaf(mPc, e0, tP0[r]);
                cT[ct] += e0;
                cP[ct]  = fmaf(mP0[r], e0, cP[ct]);

                float e1 = __builtin_amdgcn_exp2f(acc1[r] + fmaf(hi1[r], bp, -BIGNEG));
                tot1[r] += e1;
                tP1[r]  = fmaf(mPc, e1, tP1[r]);
                cT[ct] += e1;
                cP[ct]  = fmaf(mP1[r], e1, cP[ct]);
            }
        }

        // ---- row-view: butterfly over 16 col-lanes -> LDS (resolved pos) ----
        #pragma unroll
        for (int r = 0; r < 4; ++r) {
            float t0 = tot0[r], p0 = tP0[r], t1 = tot1[r], p1 = tP1[r];
            #pragma unroll
            for (int m = 1; m < 16; m <<= 1) {
                t0 += __shfl_xor(t0, m); p0 += __shfl_xor(p0, m);
                t1 += __shfl_xor(t1, m); p1 += __shfl_xor(p1, m);
            }
            if (l16 == 0) {
                int o0 = wave * 32 +      quad * 4 + r;
                int o1 = wave * 32 + 16 + quad * 4 + r;
                float li0 = lh[R * 128 + o0].x, li1 = lh[R * 128 + o1].x;
                rT[o0] = t0; rP[o0] = (li0 > 0.0f) ? p0 : (t0 - p0);
                rT[o1] = t1; rP[o1] = (li1 > 0.0f) ? p1 : (t1 - p1);
            }
        }

        // ---- col-view: reduce over quads, per-wave partials -> LDS ----
        #pragma unroll
        for (int ct = 0; ct < 8; ++ct) {
            float t = cT[ct], pp = cP[ct];
            t  += __shfl_xor(t, 16);  t  += __shfl_xor(t, 32);
            pp += __shfl_xor(pp, 16); pp += __shfl_xor(pp, 32);
            if (lane < 16) {
                int o = ct * 16 + lane;
                float lj = lhTile[o].x;
                cTl[wave][o] = t;
                cPl[wave][o] = (lj > 0.0f) ? pp : (t - pp);
            }
        }

        __syncthreads();   // aux LDS ready (also drains in-flight DMA early)

        // ---- coalesced slot stores: (stripe,slot) written exactly once ----
        if (tid < 128) {
            tpart[(size_t)C * B + R * 128 + tid] = rT[tid];
            if (R != C)
                tpart[(size_t)R * B + C * 128 + tid] =
                    cTl[0][tid] + cTl[1][tid] + cTl[2][tid] + cTl[3][tid];
        } else {
            int t2 = tid - 128;
            ppart[(size_t)C * B + R * 128 + t2] = rP[t2];
            if (R != C)
                ppart[(size_t)R * B + C * 128 + t2] =
                    cPl[0][t2] + cPl[1][t2] + cPl[2][t2] + cPl[3][t2];
        }

        __syncthreads();   // stores done; next buffer guaranteed ready

        cur ^= 1; R = Rn; C = Cn;
    }
}

// ---------------- fin1: slot-sum + per-row loss + block reduce ----------------
__global__ __launch_bounds__(256) void fin1_kernel(
    const float* __restrict__ tpart, const float* __restrict__ ppart,
    const float* __restrict__ sd, const float2* __restrict__ lh,
    float* __restrict__ accum, int B, int T)
{
    __shared__ float ssum[4], scnt[4];
    int i = blockIdx.x * 256 + threadIdx.x;

    float tot = 0.0f, pos = 0.0f;
    #pragma unroll 4
    for (int s = 0; s < T; ++s) {
        tot += tpart[(size_t)s * B + i];
        pos += ppart[(size_t)s * B + i];
    }
    float diag = (lh[i].y != 0.0f) ? __builtin_amdgcn_exp2f(sd[i]) : 0.0f;
    float p   = pos - diag;
    float neg = tot - pos;     // diag cancels (in both tot and pos)
    float sum = 0.0f, cnt = 0.0f;
    if (p > 0.0f && neg > 0.0f) {
        sum = 0.69314718055994530942f *
              (__builtin_amdgcn_logf(p + neg + 1e-8f) - __builtin_amdgcn_logf(p));
        cnt = 1.0f;
    }
    #pragma unroll
    for (int m = 32; m; m >>= 1) {
        sum += __shfl_xor(sum, m);
        cnt += __shfl_xor(cnt, m);
    }
    int wave = threadIdx.x >> 6, lane = threadIdx.x & 63;
    if (lane == 0) { ssum[wave] = sum; scnt[wave] = cnt; }
    __syncthreads();
    if (threadIdx.x == 0) {
        atomicAdd(&accum[0], ssum[0] + ssum[1] + ssum[2] + ssum[3]);
        atomicAdd(&accum[1], scnt[0] + scnt[1] + scnt[2] + scnt[3]);
    }
}

__global__ void fin2_kernel(const float* __restrict__ accum, float* __restrict__ out) {
    float S = accum[0], C = accum[1];
    out[0] = (C > 0.0f) ? S / fmaxf(C, 1.0f) : 0.0f;
}

extern "C" void kernel_launch(void* const* d_in, const int* in_sizes, int n_in,
                              void* d_out, int out_size, void* d_ws, size_t ws_size,
                              hipStream_t stream) {
    const float* emb    = (const float*)d_in[0];
    const int*   labels = (const int*)d_in[1];
    const float* conf   = (const float*)d_in[2];
    float* out = (float*)d_out;
    int B = in_sizes[1];   // 8192
    int T = B / 128;       // 64 stripes

    char* ws = (char*)d_ws;
    size_t off = 0;
    short*  Ea    = (short*)(ws + off);  off += (size_t)B * DDIM * 2;
    short*  Eb    = (short*)(ws + off);  off += (size_t)B * DDIM * 2;
    float2* lhp   = (float2*)(ws + off); off += (size_t)B * 8;
    float*  sd    = (float*)(ws + off);  off += (size_t)B * 4;
    float*  tpart = (float*)(ws + off);  off += (size_t)T * B * 4;
    float*  ppart = (float*)(ws + off);  off += (size_t)T * B * 4;
    float*  accum = (float*)(ws + off);  off += 64;

    prep_kernel<<<B / 4, 256, 0, stream>>>(emb, labels, conf, Ea, Eb, lhp, sd, accum, B);

    // persistent: 512 blocks = exactly 2/CU (73 KB LDS); consecutive pair
    // ranges (C-fastest) so A-fragments reload only on R change.
    sim_kernel<<<512, 256, 0, stream>>>(Ea, Eb, lhp, tpart, ppart, B, T);

    fin1_kernel<<<B / 256, 256, 0, stream>>>(tpart, ppart, sd, lhp, accum, B, T);
    fin2_kernel<<<1, 1, 0, stream>>>(accum, out);
}